// Round 13
// baseline (93.733 us; speedup 1.0000x reference)
//
#include <hip/hip_runtime.h>
#include <hip/hip_bf16.h>
#include <cstdint>

typedef __hip_bfloat16 bf16;
typedef __attribute__((ext_vector_type(8))) short s16x8;
typedef __attribute__((ext_vector_type(4))) float f32x4;

#define NB_B 2
#define NB_S 2048
#define NB_H 1024
#define NB_NH 16
#define NB_HD 64
#define NB_WIN 256
#define NTOK 4096

static __device__ __forceinline__ unsigned pack_bf16(float a, float b) {
    bf16 ta = __float2bfloat16(a), tb = __float2bfloat16(b);
    return (unsigned)*(unsigned short*)&ta | ((unsigned)*(unsigned short*)&tb << 16);
}
static __device__ __forceinline__ unsigned short bf16u(float a) {
    bf16 t = __float2bfloat16(a);
    return *(unsigned short*)&t;
}

#define VMCNT(n) asm volatile("s_waitcnt vmcnt(" #n ")" ::: "memory")
#define SBAR __builtin_amdgcn_s_barrier()
#define LGKM0 do { asm volatile("s_waitcnt lgkmcnt(0)" ::: "memory"); \
                   __builtin_amdgcn_sched_barrier(0); } while (0)

// ---------------- all f32->bf16 casts in one launch ----------------
__global__ void k_castall(const float* __restrict__ x, const float* __restrict__ Wq,
                          const float* __restrict__ Wk, const float* __restrict__ Wv,
                          const float* __restrict__ Wo,
                          bf16* __restrict__ xb, bf16* __restrict__ wqkvb,
                          bf16* __restrict__ wob) {
    int idx = blockIdx.x * blockDim.x + threadIdx.x;   // 0 .. 2M-1 (4 elems each)
    const float* in; bf16* out; int i;
    if (idx < 1048576)        { in = x;  out = xb;              i = idx * 4; }
    else if (idx < 1310720)   { in = Wq; out = wqkvb;           i = (idx - 1048576) * 4; }
    else if (idx < 1572864)   { in = Wk; out = wqkvb + 1048576; i = (idx - 1310720) * 4; }
    else if (idx < 1835008)   { in = Wv; out = wqkvb + 2097152; i = (idx - 1572864) * 4; }
    else                      { in = Wo; out = wob;             i = (idx - 1835008) * 4; }
    const float4 v = *(const float4*)(in + i);
    ushort4 u;
    u.x = bf16u(v.x); u.y = bf16u(v.y); u.z = bf16u(v.z); u.w = bf16u(v.w);
    *(ushort4*)((unsigned short*)out + i) = u;
}

// ===== 128x128 GEMM, BK=32, 4 rotating buffers, 1 barrier/tile =====
// Swizzle: chunk c holds logical chunk c^((row>>1)&3) (conflict-free b128).
#define GQ_STAGE(AD, BD, KT)                                                         \
    do {                                                                             \
        _Pragma("unroll")                                                            \
        for (int it_ = 0; it_ < 2; ++it_) {                                          \
            int c_ = it_ * 256 + tid;                                                \
            int row_ = c_ >> 2, pc_ = c_ & 3;                                        \
            int col_ = (pc_ ^ ((row_ >> 1) & 3)) << 3;                               \
            __builtin_amdgcn_global_load_lds(                                        \
                (const __attribute__((address_space(1))) void*)(Ap + (size_t)(m0 + row_) * 1024 + (KT) + col_), \
                (__attribute__((address_space(3))) void*)((AD) + c_ * 8), 16, 0, 0); \
            __builtin_amdgcn_global_load_lds(                                        \
                (const __attribute__((address_space(1))) void*)(Bp + (size_t)(n0 + row_) * 1024 + (KT) + col_), \
                (__attribute__((address_space(3))) void*)((BD) + c_ * 8), 16, 0, 0); \
        }                                                                            \
        __builtin_amdgcn_sched_barrier(0);                                           \
    } while (0)

#define GQ_COMPUTE(AS, BS)                                                           \
    do {                                                                             \
        const int chv_ = (g ^ ((q >> 1) & 3)) << 3;                                  \
        s16x8 af_[4], bf_[4];                                                        \
        _Pragma("unroll")                                                            \
        for (int mi_ = 0; mi_ < 4; ++mi_)                                            \
            af_[mi_] = *(const s16x8*)&(AS)[(wr * 64 + mi_ * 16 + q) * 32 + chv_];   \
        _Pragma("unroll")                                                            \
        for (int ni_ = 0; ni_ < 4; ++ni_)                                            \
            bf_[ni_] = *(const s16x8*)&(BS)[(wc * 64 + ni_ * 16 + q) * 32 + chv_];   \
        LGKM0;                                                                       \
        __builtin_amdgcn_s_setprio(1);                                               \
        _Pragma("unroll")                                                            \
        for (int mi_ = 0; mi_ < 4; ++mi_)                                            \
            _Pragma("unroll")                                                        \
            for (int ni_ = 0; ni_ < 4; ++ni_)                                        \
                acc[mi_][ni_] = __builtin_amdgcn_mfma_f32_16x16x32_bf16(             \
                    af_[mi_], bf_[ni_], acc[mi_][ni_], 0, 0, 0);                     \
        __builtin_amdgcn_s_setprio(0);                                               \
    } while (0)

// 32 tiles, 4 buffers, depth-3: [VMCNT SBAR] compute(t) stage(t+3).
// stage(t+3) targets buf((t-1)%4), last read in segment t-1, separated by the
// segment-t barrier -> WAR-safe with ONE barrier per tile. vmcnt(8) drains only
// tile t+1's 4 loads (issued 3 segments earlier); 8 newer stay in flight (T4).
#define GQ_MAINLOOP                                                                  \
    GQ_STAGE(Asb + 0 * ABUF, Bsb + 0 * BBUF, 0);                                     \
    GQ_STAGE(Asb + 1 * ABUF, Bsb + 1 * BBUF, 32);                                    \
    GQ_STAGE(Asb + 2 * ABUF, Bsb + 2 * BBUF, 64);                                    \
    VMCNT(8); SBAR;                                                                  \
    {                                                                                \
        int bc_ = 0, bs_ = 3;                                                        \
        for (int t_ = 0; t_ < 29; ++t_) {                                            \
            GQ_COMPUTE(Asb + bc_ * ABUF, Bsb + bc_ * BBUF);                          \
            GQ_STAGE(Asb + bs_ * ABUF, Bsb + bs_ * BBUF, (t_ + 3) * 32);             \
            VMCNT(8); SBAR;                                                          \
            bc_ = (bc_ + 1) & 3; bs_ = (bs_ + 1) & 3;                                \
        }                                                                            \
        GQ_COMPUTE(Asb + 1 * ABUF, Bsb + 1 * BBUF);   /* t=29 */                     \
        VMCNT(4); SBAR;                                                              \
        GQ_COMPUTE(Asb + 2 * ABUF, Bsb + 2 * BBUF);   /* t=30 */                     \
        VMCNT(0); SBAR;                                                              \
        GQ_COMPUTE(Asb + 3 * ABUF, Bsb + 3 * BBUF);   /* t=31 */                     \
    }

// ---------------- fused QKV GEMM + bias + QK-LayerNorm + V-transpose ----------
__global__ __launch_bounds__(256, 2) void k_gemm_qkv(const bf16* __restrict__ Ap,
                                                  const bf16* __restrict__ Bp,
                                                  const float* __restrict__ bq,
                                                  const float* __restrict__ bk,
                                                  const float* __restrict__ bv,
                                                  const float* __restrict__ lqw,
                                                  const float* __restrict__ lqb,
                                                  const float* __restrict__ lkw,
                                                  const float* __restrict__ lkb,
                                                  bf16* __restrict__ qbuf,
                                                  bf16* __restrict__ kbuf,
                                                  bf16* __restrict__ vtb) {
    const int ABUF = 128 * 32, BBUF = 128 * 32;
    __shared__ bf16 Asb[4 * 128 * 32];
    __shared__ bf16 Bsb[4 * 128 * 32];
    const int tid = threadIdx.x;
    const int lane = tid & 63;
    const int w = tid >> 6;
    const int wr = w >> 1, wc = w & 1;

    const int orig = blockIdx.y * gridDim.x + blockIdx.x;   // 768 blocks
    const int wk = (orig & 7) * 96 + (orig >> 3);           // bijective
    const int m0 = (wk / 24) * 128, n0 = (wk % 24) * 128;

    const int g = lane >> 4, q = lane & 15;

    f32x4 acc[4][4] = {};

    GQ_MAINLOOP;

    // ---------------- fused epilogue ----------------
    const int col0 = n0 + wc * 64;        // head-aligned (64 | col0)
    const int hh = col0 >> 6;             // 0..47
    const int csub = col0 & 1023;
    const float* bias = (hh < 16) ? bq : (hh < 32) ? bk : bv;

    float bcol[4];
#pragma unroll
    for (int ni = 0; ni < 4; ++ni) bcol[ni] = bias[csub + ni * 16 + q];
#pragma unroll
    for (int mi = 0; mi < 4; ++mi)
#pragma unroll
        for (int ni = 0; ni < 4; ++ni)
#pragma unroll
            for (int r = 0; r < 4; ++r) acc[mi][ni][r] += bcol[ni];

    if (hh < 32) {
        const float* gwa = (hh < 16) ? lqw : lkw;
        const float* gba = (hh < 16) ? lqb : lkb;
        float gam[4], bet[4];
#pragma unroll
        for (int ni = 0; ni < 4; ++ni) {
            gam[ni] = gwa[ni * 16 + q];
            bet[ni] = gba[ni * 16 + q];
        }
        bf16* outp = (hh < 16) ? qbuf : kbuf;
#pragma unroll
        for (int mi = 0; mi < 4; ++mi)
#pragma unroll
            for (int r = 0; r < 4; ++r) {
                float s1 = acc[mi][0][r] + acc[mi][1][r] + acc[mi][2][r] + acc[mi][3][r];
                float s2 = acc[mi][0][r] * acc[mi][0][r] + acc[mi][1][r] * acc[mi][1][r]
                         + acc[mi][2][r] * acc[mi][2][r] + acc[mi][3][r] * acc[mi][3][r];
#pragma unroll
                for (int mm = 1; mm < 16; mm <<= 1) {
                    s1 += __shfl_xor(s1, mm, 64);
                    s2 += __shfl_xor(s2, mm, 64);
                }
                float mean = s1 * (1.f / 64.f);
                float var = s2 * (1.f / 64.f) - mean * mean;
                float rs = rsqrtf(var + 1e-5f);
                int token = m0 + wr * 64 + mi * 16 + g * 4 + r;
#pragma unroll
                for (int ni = 0; ni < 4; ++ni) {
                    float y = (acc[mi][ni][r] - mean) * rs * gam[ni] + bet[ni];
                    outp[(size_t)token * 1024 + csub + ni * 16 + q] = __float2bfloat16(y);
                }
            }
    } else {
        // V: transposed write vt[bh][d][s], 4 consecutive tokens packed per store
        const int b = m0 >> 11;
        const int bh = b * 16 + (csub >> 6);
        const int sbase0 = (m0 & 2047) + wr * 64 + g * 4;
#pragma unroll
        for (int mi = 0; mi < 4; ++mi) {
            const int sb = sbase0 + mi * 16;
#pragma unroll
            for (int ni = 0; ni < 4; ++ni) {
                const int d = ni * 16 + q;
                ushort4 u;
                u.x = bf16u(acc[mi][ni][0]); u.y = bf16u(acc[mi][ni][1]);
                u.z = bf16u(acc[mi][ni][2]); u.w = bf16u(acc[mi][ni][3]);
                *(ushort4*)(vtb + ((size_t)bh * 64 + d) * 2048 + sb) = u;
            }
        }
    }
}

// ===== out-proj: 128x64 tile, BK=32, 4 buffers, 1 barrier/tile =====
#define GO_STAGE(AD, BD, KT)                                                         \
    do {                                                                             \
        _Pragma("unroll")                                                            \
        for (int it_ = 0; it_ < 2; ++it_) {                                          \
            int c_ = it_ * 256 + tid;                                                \
            int row_ = c_ >> 2, pc_ = c_ & 3;                                        \
            int col_ = (pc_ ^ ((row_ >> 1) & 3)) << 3;                               \
            __builtin_amdgcn_global_load_lds(                                        \
                (const __attribute__((address_space(1))) void*)(Ap + (size_t)(m0 + row_) * 1024 + (KT) + col_), \
                (__attribute__((address_space(3))) void*)((AD) + c_ * 8), 16, 0, 0); \
        }                                                                            \
        {                                                                            \
            int row_ = tid >> 2, pc_ = tid & 3;                                      \
            int col_ = (pc_ ^ ((row_ >> 1) & 3)) << 3;                               \
            __builtin_amdgcn_global_load_lds(                                        \
                (const __attribute__((address_space(1))) void*)(Bp + (size_t)(n0 + row_) * 1024 + (KT) + col_), \
                (__attribute__((address_space(3))) void*)((BD) + tid * 8), 16, 0, 0); \
        }                                                                            \
        __builtin_amdgcn_sched_barrier(0);                                           \
    } while (0)

#define GO_COMPUTE(AS, BS)                                                           \
    do {                                                                             \
        const int chv_ = (g ^ ((q >> 1) & 3)) << 3;                                  \
        s16x8 af_[4], bf_[2];                                                        \
        _Pragma("unroll")                                                            \
        for (int mi_ = 0; mi_ < 4; ++mi_)                                            \
            af_[mi_] = *(const s16x8*)&(AS)[(wr * 64 + mi_ * 16 + q) * 32 + chv_];   \
        _Pragma("unroll")                                                            \
        for (int ni_ = 0; ni_ < 2; ++ni_)                                            \
            bf_[ni_] = *(const s16x8*)&(BS)[(wc * 32 + ni_ * 16 + q) * 32 + chv_];   \
        LGKM0;                                                                       \
        __builtin_amdgcn_s_setprio(1);                                               \
        _Pragma("unroll")                                                            \
        for (int mi_ = 0; mi_ < 4; ++mi_)                                            \
            _Pragma("unroll")                                                        \
            for (int ni_ = 0; ni_ < 2; ++ni_)                                        \
                acc[mi_][ni_] = __builtin_amdgcn_mfma_f32_16x16x32_bf16(             \
                    af_[mi_], bf_[ni_], acc[mi_][ni_], 0, 0, 0);                     \
        __builtin_amdgcn_s_setprio(0);                                               \
    } while (0)

#define GO_MAINLOOP                                                                  \
    GO_STAGE(Asb + 0 * ABUF, Bsb + 0 * BBUF, 0);                                     \
    GO_STAGE(Asb + 1 * ABUF, Bsb + 1 * BBUF, 32);                                    \
    GO_STAGE(Asb + 2 * ABUF, Bsb + 2 * BBUF, 64);                                    \
    VMCNT(6); SBAR;                                                                  \
    {                                                                                \
        int bc_ = 0, bs_ = 3;                                                        \
        for (int t_ = 0; t_ < 29; ++t_) {                                            \
            GO_COMPUTE(Asb + bc_ * ABUF, Bsb + bc_ * BBUF);                          \
            GO_STAGE(Asb + bs_ * ABUF, Bsb + bs_ * BBUF, (t_ + 3) * 32);             \
            VMCNT(6); SBAR;                                                          \
            bc_ = (bc_ + 1) & 3; bs_ = (bs_ + 1) & 3;                                \
        }                                                                            \
        GO_COMPUTE(Asb + 1 * ABUF, Bsb + 1 * BBUF);   /* t=29 */                     \
        VMCNT(3); SBAR;                                                              \
        GO_COMPUTE(Asb + 2 * ABUF, Bsb + 2 * BBUF);   /* t=30 */                     \
        VMCNT(0); SBAR;                                                              \
        GO_COMPUTE(Asb + 3 * ABUF, Bsb + 3 * BBUF);   /* t=31 */                     \
    }

__global__ __launch_bounds__(256, 2) void k_gemm_out(const bf16* __restrict__ Ap,
                                                  const bf16* __restrict__ Bp,
                                                  const float* __restrict__ bias,
                                                  float* __restrict__ Cv) {
    const int ABUF = 128 * 32, BBUF = 64 * 32;
    __shared__ bf16 Asb[4 * 128 * 32];
    __shared__ bf16 Bsb[4 * 64 * 32];
    const int tid = threadIdx.x;
    const int lane = tid & 63;
    const int w = tid >> 6;
    const int wr = w >> 1, wc = w & 1;

    const int orig = blockIdx.y * gridDim.x + blockIdx.x;   // 512 blocks
    const int wk = (orig & 7) * 64 + (orig >> 3);
    const int m0 = (wk / 16) * 128, n0 = (wk % 16) * 64;

    const int g = lane >> 4, q = lane & 15;

    f32x4 acc[4][2] = {};

    GO_MAINLOOP;

#pragma unroll
    for (int mi = 0; mi < 4; ++mi)
#pragma unroll
        for (int ni = 0; ni < 2; ++ni) {
            int colg = n0 + wc * 32 + ni * 16 + q;
            float bcol = bias[colg];
#pragma unroll
            for (int r = 0; r < 4; ++r) {
                int rowg = m0 + wr * 64 + mi * 16 + g * 4 + r;
                Cv[(size_t)rowg * 1024 + colg] = acc[mi][ni][r] + bcol;
            }
        }
}

#undef GQ_STAGE
#undef GQ_COMPUTE
#undef GQ_MAINLOOP
#undef GO_STAGE
#undef GO_COMPUTE
#undef GO_MAINLOOP

// ---------------- windowed causal flash attention v4 ----------------
// 4-buffer K/V rotation, depth-3 prefetch, ONE barrier per chunk.
// Segment c: [VMCNT(ahead) SBAR] compute(c) stage(c+3). stage target
// buf((c-1)&3) was last read in segment c-1, separated by this segment's
// barrier -> WAR-safe. ahead = staged-c chooses vmcnt(4)/(2)/(0), uniform.
__global__ __launch_bounds__(256) void k_attn(const bf16* __restrict__ qb,
                                              const bf16* __restrict__ kb,
                                              const bf16* __restrict__ vt,
                                              bf16* __restrict__ att) {
    __shared__ bf16 Ks[4][32 * 64];
    __shared__ bf16 Vs[4][64 * 32];

    const int orig = blockIdx.y * gridDim.x + blockIdx.x;
    const int wk = (orig & 7) * 128 + (orig >> 3);  // bijective: 1024 % 8 == 0
    const int q0 = (wk & 31) * 64;
    const int bh = wk >> 5;

    const int b = bh >> 4, h = bh & 15;
    const int tid = threadIdx.x;
    const int w = tid >> 6;
    const int lane = tid & 63;
    const int g = lane >> 4, qi = lane & 15;
    const int qw0 = q0 + w * 16;
    const int iq = qw0 + qi;

    const size_t qbase = ((size_t)(b * 2048 + iq)) * 1024 + h * 64 + g * 8;
    s16x8 bq0 = *(const s16x8*)(qb + qbase);
    s16x8 bq1 = *(const s16x8*)(qb + qbase + 32);

    f32x4 o[4] = {};
    float lp = 0.f;

    int jmin = q0 - NB_WIN; if (jmin < 0) jmin = 0;
    const int c0 = jmin >> 5;
    const int c1 = (q0 + 63) >> 5;

    const int krow = tid >> 3, kpc = tid & 7;
    const int kcol = ((kpc ^ (krow & 7)) << 3);
    const int vrow = tid >> 2, vpc = tid & 3;
    const int vcol = ((vpc ^ (vrow & 3)) << 3);
    const bf16* kbase = kb + ((size_t)(b * 2048 + krow)) * 1024 + h * 64 + kcol;
    const bf16* vbase = vt + ((size_t)bh * 64 + vrow) * 2048 + vcol;

#define ATTN_STAGE(C)                                                                \
    do {                                                                             \
        const int bf_ = (C) & 3;                                                     \
        __builtin_amdgcn_global_load_lds(                                            \
            (const __attribute__((address_space(1))) void*)(kbase + (size_t)((C) * 32) * 1024), \
            (__attribute__((address_space(3))) void*)(&Ks[bf_][tid * 8]), 16, 0, 0); \
        __builtin_amdgcn_global_load_lds(                                            \
            (const __attribute__((address_space(1))) void*)(vbase + (C) * 32),       \
            (__attribute__((address_space(3))) void*)(&Vs[bf_][tid * 8]), 16, 0, 0); \
        __builtin_amdgcn_sched_barrier(0);                                           \
    } while (0)

    // prologue: stage up to 3 chunks
    int staged = c0 + 2; if (staged > c1) staged = c1;
    ATTN_STAGE(c0);
    if (c0 + 1 <= c1) ATTN_STAGE(c0 + 1);
    if (c0 + 2 <= c1) ATTN_STAGE(c0 + 2);

    for (int c = c0; c <= c1; ++c) {
        const int ahead = staged - c;      // uniform across block
        if (ahead >= 2)      { VMCNT(4); }
        else if (ahead == 1) { VMCNT(2); }
        else                 { VMCNT(0); }
        SBAR;

        const int ks = c * 32;
        const int buf = c & 3;
        if (ks + 31 >= qw0 - NB_WIN && ks <= qw0 + 15) {
            const int ch0 = ((g ^ (qi & 7)) << 3);
            const bf16* kr0 = &Ks[buf][qi * 64];
            const bf16* kr1 = &Ks[buf][(16 + qi) * 64];
            s16x8 a00 = *(const s16x8*)(kr0 + ch0);
            s16x8 a01 = *(const s16x8*)(kr0 + (ch0 ^ 32));
            s16x8 a10 = *(const s16x8*)(kr1 + ch0);
            s16x8 a11 = *(const s16x8*)(kr1 + (ch0 ^ 32));

            f32x4 s0 = {}, s1 = {};
            s0 = __builtin_amdgcn_mfma_f32_16x16x32_bf16(a00, bq0, s0, 0, 0, 0);
            s0 = __builtin_amdgcn_mfma_f32_16x16x32_bf16(a01, bq1, s0, 0, 0, 0);
            s1 = __builtin_amdgcn_mfma_f32_16x16x32_bf16(a10, bq0, s1, 0, 0, 0);
            s1 = __builtin_amdgcn_mfma_f32_16x16x32_bf16(a11, bq1, s1, 0, 0, 0);

            float p0[4], p1[4];
#pragma unroll
            for (int r = 0; r < 4; ++r) {
                int j0 = ks + 4 * g + r, j1 = j0 + 16;
                p0[r] = ((unsigned)(iq - j0) <= (unsigned)NB_WIN)
                            ? __expf(s0[r] * 0.125f - 8.f) : 0.f;
                p1[r] = ((unsigned)(iq - j1) <= (unsigned)NB_WIN)
                            ? __expf(s1[r] * 0.125f - 8.f) : 0.f;
                lp += p0[r] + p1[r];
            }
            unsigned P0 = pack_bf16(p0[0], p0[1]), P1 = pack_bf16(p0[2], p0[3]);
            unsigned Q0 = pack_bf16(p1[0], p1[1]), Q1 = pack_bf16(p1[2], p1[3]);

            const int srcA = qi + (g & 1) * 32;
            const int srcB = srcA + 16;
            unsigned tP0a = __shfl((int)P0, srcA, 64), tQ0a = __shfl((int)Q0, srcA, 64);
            unsigned tP1a = __shfl((int)P1, srcA, 64), tQ1a = __shfl((int)Q1, srcA, 64);
            unsigned tP0b = __shfl((int)P0, srcB, 64), tQ0b = __shfl((int)Q0, srcB, 64);
            unsigned tP1b = __shfl((int)P1, srcB, 64), tQ1b = __shfl((int)Q1, srcB, 64);
            union { s16x8 v; unsigned u[4]; } pa;
            pa.u[0] = (g < 2) ? tP0a : tQ0a;
            pa.u[1] = (g < 2) ? tP1a : tQ1a;
            pa.u[2] = (g < 2) ? tP0b : tQ0b;
            pa.u[3] = (g < 2) ? tP1b : tQ1b;

            const int chv = ((g ^ (qi & 3)) << 3);
#pragma unroll
            for (int db = 0; db < 4; ++db) {
                s16x8 bv = *(const s16x8*)&Vs[buf][(db * 16 + qi) * 32 + chv];
                o[db] = __builtin_amdgcn_mfma_f32_16x16x32_bf16(pa.v, bv, o[db], 0, 0, 0);
            }
        }

        if (staged < c1) { ++staged; ATTN_STAGE(staged); }
    }
#undef ATTN_STAGE

    float l2 = lp + __shfl_xor(lp, 16, 64);
    float lf = l2 + __shfl_xor(l2, 32, 64);
    float lr[4];
#pragma unroll
    for (int r = 0; r < 4; ++r) lr[r] = __shfl(lf, 4 * g + r, 64);

#pragma unroll
    for (int db = 0; db < 4; ++db)
#pragma unroll
        for (int r = 0; r < 4; ++r) {
            float vlu = o[db][r] / lr[r];
            att[((size_t)(b * 2048 + qw0 + 4 * g + r)) * 1024 + h * 64 + db * 16 + qi] =
                __float2bfloat16(vlu);
        }
}

extern "C" void kernel_launch(void* const* d_in, const int* in_sizes, int n_in,
                              void* d_out, int out_size, void* d_ws, size_t ws_size,
                              hipStream_t stream) {
    const float* x   = (const float*)d_in[0];
    const float* Wq  = (const float*)d_in[1];
    const float* bq  = (const float*)d_in[2];
    const float* Wk  = (const float*)d_in[3];
    const float* bk  = (const float*)d_in[4];
    const float* Wv  = (const float*)d_in[5];
    const float* bv  = (const float*)d_in[6];
    const float* Wo  = (const float*)d_in[7];
    const float* bo  = (const float*)d_in[8];
    const float* lqw = (const float*)d_in[9];
    const float* lqb = (const float*)d_in[10];
    const float* lkw = (const float*)d_in[11];
    const float* lkb = (const float*)d_in[12];

    char* ws = (char*)d_ws;
    bf16* xb    = (bf16*)(ws + 0);               //  8 MB
    bf16* wqkvb = (bf16*)(ws + 8388608);         //  6 MB (Wq|Wk|Wv rows)
    bf16* wob   = (bf16*)(ws + 14680064);        //  2 MB
    bf16* qbuf  = (bf16*)(ws + 16777216);        //  8 MB
    bf16* kbuf  = (bf16*)(ws + 25165824);        //  8 MB
    bf16* vtb   = (bf16*)(ws + 33554432);        //  8 MB
    bf16* attb  = (bf16*)(ws + 41943040);        //  8 MB  (total ~48 MB)

    // all casts in one launch (2M threads)
    k_castall<<<8192, 256, 0, stream>>>(x, Wq, Wk, Wv, Wo, xb, wqkvb, wob);

    // fused QKV projection + bias + QK-LN + V-transpose (4-buf, 1 barrier/tile)
    k_gemm_qkv<<<dim3(24, 32), 256, 0, stream>>>(xb, wqkvb, bq, bk, bv,
                                                 lqw, lqb, lkw, lkb,
                                                 qbuf, kbuf, vtb);

    // attention: 1024 blocks (4-buf, 1 barrier/chunk)
    k_attn<<<dim3(32, 32), 256, 0, stream>>>(qbuf, kbuf, vtb, attb);

    // output projection -> f32 d_out (4-buf, 1 barrier/tile)
    k_gemm_out<<<dim3(16, 32), 256, 0, stream>>>(attb, wob, bo, (float*)d_out);
}

// Round 14
// 89.924 us; speedup vs baseline: 1.0424x; 1.0424x over previous
//
#include <hip/hip_runtime.h>
#include <hip/hip_bf16.h>
#include <cstdint>

typedef __hip_bfloat16 bf16;
typedef __attribute__((ext_vector_type(8))) short s16x8;
typedef __attribute__((ext_vector_type(4))) float f32x4;

#define NB_B 2
#define NB_S 2048
#define NB_H 1024
#define NB_NH 16
#define NB_HD 64
#define NB_WIN 256
#define NTOK 4096

static __device__ __forceinline__ unsigned pack_bf16(float a, float b) {
    bf16 ta = __float2bfloat16(a), tb = __float2bfloat16(b);
    return (unsigned)*(unsigned short*)&ta | ((unsigned)*(unsigned short*)&tb << 16);
}
static __device__ __forceinline__ unsigned short bf16u(float a) {
    bf16 t = __float2bfloat16(a);
    return *(unsigned short*)&t;
}

#define VMCNT(n) asm volatile("s_waitcnt vmcnt(" #n ")" ::: "memory")
#define SBAR __builtin_amdgcn_s_barrier()

// ---------------- all f32->bf16 casts in one launch ----------------
__global__ void k_castall(const float* __restrict__ x, const float* __restrict__ Wq,
                          const float* __restrict__ Wk, const float* __restrict__ Wv,
                          const float* __restrict__ Wo,
                          bf16* __restrict__ xb, bf16* __restrict__ wqkvb,
                          bf16* __restrict__ wob) {
    int idx = blockIdx.x * blockDim.x + threadIdx.x;   // 0 .. 2M-1 (4 elems each)
    const float* in; bf16* out; int i;
    if (idx < 1048576)        { in = x;  out = xb;              i = idx * 4; }
    else if (idx < 1310720)   { in = Wq; out = wqkvb;           i = (idx - 1048576) * 4; }
    else if (idx < 1572864)   { in = Wk; out = wqkvb + 1048576; i = (idx - 1310720) * 4; }
    else if (idx < 1835008)   { in = Wv; out = wqkvb + 2097152; i = (idx - 1572864) * 4; }
    else                      { in = Wo; out = wob;             i = (idx - 1835008) * 4; }
    const float4 v = *(const float4*)(in + i);
    ushort4 u;
    u.x = bf16u(v.x); u.y = bf16u(v.y); u.z = bf16u(v.z); u.w = bf16u(v.w);
    *(ushort4*)((unsigned short*)out + i) = u;
}

// STAGE: issue 8 global_load_lds (A+B tile, XOR-swizzled source, linear dest).
#define G_STAGE(AD, BD, KT)                                                          \
    do {                                                                             \
        _Pragma("unroll")                                                            \
        for (int it_ = 0; it_ < 4; ++it_) {                                          \
            int c_ = it_ * 256 + tid;                                                \
            int row_ = c_ >> 3, pc_ = c_ & 7;                                        \
            int col_ = ((pc_ ^ (row_ & 7)) << 3);                                    \
            __builtin_amdgcn_global_load_lds(                                        \
                (const __attribute__((address_space(1))) void*)(Ap + (size_t)(m0 + row_) * 1024 + (KT) + col_), \
                (__attribute__((address_space(3))) void*)((AD) + c_ * 8), 16, 0, 0); \
            __builtin_amdgcn_global_load_lds(                                        \
                (const __attribute__((address_space(1))) void*)(Bp + (size_t)(n0 + row_) * 1024 + (KT) + col_), \
                (__attribute__((address_space(3))) void*)((BD) + c_ * 8), 16, 0, 0); \
        }                                                                            \
        __builtin_amdgcn_sched_barrier(0);                                           \
    } while (0)

// COMPUTE: 16 ds_read_b128 + 32 MFMA (setprio-wrapped), matching XOR on reads.
#define G_COMPUTE(AS, BS)                                                            \
    do {                                                                             \
        _Pragma("unroll")                                                            \
        for (int kk_ = 0; kk_ < 2; ++kk_) {                                          \
            const int rchunk_ = (((kk_ << 2) + g) ^ (q & 7)) << 3;                   \
            s16x8 af_[4], bf_[4];                                                    \
            _Pragma("unroll")                                                        \
            for (int mi_ = 0; mi_ < 4; ++mi_)                                        \
                af_[mi_] = *(const s16x8*)&(AS)[(wr * 64 + mi_ * 16 + q) * 64 + rchunk_]; \
            _Pragma("unroll")                                                        \
            for (int ni_ = 0; ni_ < 4; ++ni_)                                        \
                bf_[ni_] = *(const s16x8*)&(BS)[(wc * 64 + ni_ * 16 + q) * 64 + rchunk_]; \
            __builtin_amdgcn_s_setprio(1);                                           \
            _Pragma("unroll")                                                        \
            for (int mi_ = 0; mi_ < 4; ++mi_)                                        \
                _Pragma("unroll")                                                    \
                for (int ni_ = 0; ni_ < 4; ++ni_)                                    \
                    acc[mi_][ni_] = __builtin_amdgcn_mfma_f32_16x16x32_bf16(         \
                        af_[mi_], bf_[ni_], acc[mi_][ni_], 0, 0, 0);                 \
            __builtin_amdgcn_s_setprio(0);                                           \
        }                                                                            \
    } while (0)

// Counted-vmcnt pipelined K-loop (K=1024, BK=64, 16 tiles, prefetch depth 2).
// Steady state: 16 loads in flight; vmcnt(8) waits the OLDER tile only.
// Never drains to 0 in the main loop (T4); raw s_barrier, no __syncthreads.
#define G_MAINLOOP                                                                   \
    G_STAGE(As0, Bs0, 0);                                                            \
    G_STAGE(As1, Bs1, 64);                                                           \
    for (int i_ = 0; i_ < 7; ++i_) {                                                 \
        const int kt_ = i_ * 128;                                                    \
        VMCNT(8); SBAR;                                                              \
        G_COMPUTE(As0, Bs0);                                                         \
        SBAR;                                                                        \
        G_STAGE(As0, Bs0, kt_ + 128);                                                \
        VMCNT(8); SBAR;                                                              \
        G_COMPUTE(As1, Bs1);                                                         \
        SBAR;                                                                        \
        G_STAGE(As1, Bs1, kt_ + 192);                                                \
    }                                                                                \
    VMCNT(8); SBAR;                                                                  \
    G_COMPUTE(As0, Bs0);                                                             \
    VMCNT(0); SBAR;                                                                  \
    G_COMPUTE(As1, Bs1)

// ---------------- fused QKV GEMM + bias + QK-LayerNorm + V-transpose ----------
__global__ __launch_bounds__(256) void k_gemm_qkv(const bf16* __restrict__ Ap,
                                                  const bf16* __restrict__ Bp,
                                                  const float* __restrict__ bq,
                                                  const float* __restrict__ bk,
                                                  const float* __restrict__ bv,
                                                  const float* __restrict__ lqw,
                                                  const float* __restrict__ lqb,
                                                  const float* __restrict__ lkw,
                                                  const float* __restrict__ lkb,
                                                  bf16* __restrict__ qbuf,
                                                  bf16* __restrict__ kbuf,
                                                  bf16* __restrict__ vtb) {
    __shared__ bf16 As0[128 * 64], As1[128 * 64];
    __shared__ bf16 Bs0[128 * 64], Bs1[128 * 64];
    const int tid = threadIdx.x;
    const int lane = tid & 63;
    const int w = tid >> 6;
    const int wr = w >> 1, wc = w & 1;

    const int orig = blockIdx.y * gridDim.x + blockIdx.x;   // 768 blocks
    const int wk = (orig & 7) * 96 + (orig >> 3);           // bijective
    const int m0 = (wk / 24) * 128, n0 = (wk % 24) * 128;

    const int g = lane >> 4, q = lane & 15;

    f32x4 acc[4][4] = {};

    G_MAINLOOP;

    // ---------------- fused epilogue ----------------
    const int col0 = n0 + wc * 64;        // head-aligned (64 | col0)
    const int hh = col0 >> 6;             // 0..47
    const int csub = col0 & 1023;
    const float* bias = (hh < 16) ? bq : (hh < 32) ? bk : bv;

    float bcol[4];
#pragma unroll
    for (int ni = 0; ni < 4; ++ni) bcol[ni] = bias[csub + ni * 16 + q];
#pragma unroll
    for (int mi = 0; mi < 4; ++mi)
#pragma unroll
        for (int ni = 0; ni < 4; ++ni)
#pragma unroll
            for (int r = 0; r < 4; ++r) acc[mi][ni][r] += bcol[ni];

    if (hh < 32) {
        const float* gwa = (hh < 16) ? lqw : lkw;
        const float* gba = (hh < 16) ? lqb : lkb;
        float gam[4], bet[4];
#pragma unroll
        for (int ni = 0; ni < 4; ++ni) {
            gam[ni] = gwa[ni * 16 + q];
            bet[ni] = gba[ni * 16 + q];
        }
        bf16* outp = (hh < 16) ? qbuf : kbuf;
#pragma unroll
        for (int mi = 0; mi < 4; ++mi)
#pragma unroll
            for (int r = 0; r < 4; ++r) {
                float s1 = acc[mi][0][r] + acc[mi][1][r] + acc[mi][2][r] + acc[mi][3][r];
                float s2 = acc[mi][0][r] * acc[mi][0][r] + acc[mi][1][r] * acc[mi][1][r]
                         + acc[mi][2][r] * acc[mi][2][r] + acc[mi][3][r] * acc[mi][3][r];
#pragma unroll
                for (int mm = 1; mm < 16; mm <<= 1) {
                    s1 += __shfl_xor(s1, mm, 64);
                    s2 += __shfl_xor(s2, mm, 64);
                }
                float mean = s1 * (1.f / 64.f);
                float var = s2 * (1.f / 64.f) - mean * mean;
                float rs = rsqrtf(var + 1e-5f);
                int token = m0 + wr * 64 + mi * 16 + g * 4 + r;
#pragma unroll
                for (int ni = 0; ni < 4; ++ni) {
                    float y = (acc[mi][ni][r] - mean) * rs * gam[ni] + bet[ni];
                    outp[(size_t)token * 1024 + csub + ni * 16 + q] = __float2bfloat16(y);
                }
            }
    } else {
        // V: transposed write vt[bh][d][s], 4 consecutive tokens packed per store
        const int b = m0 >> 11;
        const int bh = b * 16 + (csub >> 6);
        const int sbase0 = (m0 & 2047) + wr * 64 + g * 4;
#pragma unroll
        for (int mi = 0; mi < 4; ++mi) {
            const int sb = sbase0 + mi * 16;
#pragma unroll
            for (int ni = 0; ni < 4; ++ni) {
                const int d = ni * 16 + q;
                ushort4 u;
                u.x = bf16u(acc[mi][ni][0]); u.y = bf16u(acc[mi][ni][1]);
                u.z = bf16u(acc[mi][ni][2]); u.w = bf16u(acc[mi][ni][3]);
                *(ushort4*)(vtb + ((size_t)bh * 64 + d) * 2048 + sb) = u;
            }
        }
    }
}

// ---------------- output projection GEMM (f32 out) ----------------
__global__ __launch_bounds__(256) void k_gemm_out(const bf16* __restrict__ Ap,
                                                  const bf16* __restrict__ Bp,
                                                  const float* __restrict__ bias,
                                                  float* __restrict__ Cv) {
    __shared__ bf16 As0[128 * 64], As1[128 * 64];
    __shared__ bf16 Bs0[128 * 64], Bs1[128 * 64];
    const int tid = threadIdx.x;
    const int lane = tid & 63;
    const int w = tid >> 6;
    const int wr = w >> 1, wc = w & 1;

    const int orig = blockIdx.y * gridDim.x + blockIdx.x;   // 256 blocks
    const int wk = (orig & 7) * 32 + (orig >> 3);
    const int m0 = (wk / 8) * 128, n0 = (wk % 8) * 128;

    const int g = lane >> 4, q = lane & 15;

    f32x4 acc[4][4] = {};

    G_MAINLOOP;

#pragma unroll
    for (int mi = 0; mi < 4; ++mi)
#pragma unroll
        for (int ni = 0; ni < 4; ++ni) {
            int colg = n0 + wc * 64 + ni * 16 + q;
            float bcol = bias[colg];
#pragma unroll
            for (int r = 0; r < 4; ++r) {
                int rowg = m0 + wr * 64 + mi * 16 + g * 4 + r;
                Cv[(size_t)rowg * 1024 + colg] = acc[mi][ni][r] + bcol;
            }
        }
}

#undef G_STAGE
#undef G_COMPUTE
#undef G_MAINLOOP

// ---------------- windowed causal flash attention v3 (counted vmcnt) ----------
__global__ __launch_bounds__(256) void k_attn(const bf16* __restrict__ qb,
                                              const bf16* __restrict__ kb,
                                              const bf16* __restrict__ vt,
                                              bf16* __restrict__ att) {
    __shared__ bf16 Ks[2][32 * 64];
    __shared__ bf16 Vs[2][64 * 32];

    const int orig = blockIdx.y * gridDim.x + blockIdx.x;
    const int wk = (orig & 7) * 128 + (orig >> 3);  // bijective: 1024 % 8 == 0
    const int q0 = (wk & 31) * 64;
    const int bh = wk >> 5;

    const int b = bh >> 4, h = bh & 15;
    const int tid = threadIdx.x;
    const int w = tid >> 6;
    const int lane = tid & 63;
    const int g = lane >> 4, qi = lane & 15;
    const int qw0 = q0 + w * 16;
    const int iq = qw0 + qi;

    const size_t qbase = ((size_t)(b * 2048 + iq)) * 1024 + h * 64 + g * 8;
    s16x8 bq0 = *(const s16x8*)(qb + qbase);
    s16x8 bq1 = *(const s16x8*)(qb + qbase + 32);

    f32x4 o[4] = {};
    float lp = 0.f;

    int jmin = q0 - NB_WIN; if (jmin < 0) jmin = 0;
    const int c0 = jmin >> 5;
    const int c1 = (q0 + 63) >> 5;

    const int krow = tid >> 3, kpc = tid & 7;
    const int kcol = ((kpc ^ (krow & 7)) << 3);
    const int vrow = tid >> 2, vpc = tid & 3;
    const int vcol = ((vpc ^ (vrow & 3)) << 3);
    const bf16* kbase = kb + ((size_t)(b * 2048 + krow)) * 1024 + h * 64 + kcol;
    const bf16* vbase = vt + ((size_t)bh * 64 + vrow) * 2048 + vcol;

    __builtin_amdgcn_global_load_lds(
        (const __attribute__((address_space(1))) void*)(kbase + (size_t)(c0 * 32) * 1024),
        (__attribute__((address_space(3))) void*)(&Ks[0][tid * 8]), 16, 0, 0);
    __builtin_amdgcn_global_load_lds(
        (const __attribute__((address_space(1))) void*)(vbase + c0 * 32),
        (__attribute__((address_space(3))) void*)(&Vs[0][tid * 8]), 16, 0, 0);

    int buf = 0;
    for (int c = c0; c <= c1; ++c) {
        const int ks = c * 32;
        if (c < c1) {
            const int ksn = ks + 32;
            __builtin_amdgcn_global_load_lds(
                (const __attribute__((address_space(1))) void*)(kbase + (size_t)ksn * 1024),
                (__attribute__((address_space(3))) void*)(&Ks[buf ^ 1][tid * 8]), 16, 0, 0);
            __builtin_amdgcn_global_load_lds(
                (const __attribute__((address_space(1))) void*)(vbase + ksn),
                (__attribute__((address_space(3))) void*)(&Vs[buf ^ 1][tid * 8]), 16, 0, 0);
            __builtin_amdgcn_sched_barrier(0);
            VMCNT(2);   // current chunk's 2 loads done; prefetch stays in flight
        } else {
            VMCNT(0);   // last chunk: drain
        }
        SBAR;

        if (ks + 31 >= qw0 - NB_WIN && ks <= qw0 + 15) {
            const int ch0 = ((g ^ (qi & 7)) << 3);
            const bf16* kr0 = &Ks[buf][qi * 64];
            const bf16* kr1 = &Ks[buf][(16 + qi) * 64];
            s16x8 a00 = *(const s16x8*)(kr0 + ch0);
            s16x8 a01 = *(const s16x8*)(kr0 + (ch0 ^ 32));
            s16x8 a10 = *(const s16x8*)(kr1 + ch0);
            s16x8 a11 = *(const s16x8*)(kr1 + (ch0 ^ 32));

            f32x4 s0 = {}, s1 = {};
            s0 = __builtin_amdgcn_mfma_f32_16x16x32_bf16(a00, bq0, s0, 0, 0, 0);
            s0 = __builtin_amdgcn_mfma_f32_16x16x32_bf16(a01, bq1, s0, 0, 0, 0);
            s1 = __builtin_amdgcn_mfma_f32_16x16x32_bf16(a10, bq0, s1, 0, 0, 0);
            s1 = __builtin_amdgcn_mfma_f32_16x16x32_bf16(a11, bq1, s1, 0, 0, 0);

            float p0[4], p1[4];
#pragma unroll
            for (int r = 0; r < 4; ++r) {
                int j0 = ks + 4 * g + r, j1 = j0 + 16;
                p0[r] = ((unsigned)(iq - j0) <= (unsigned)NB_WIN)
                            ? __expf(s0[r] * 0.125f - 8.f) : 0.f;
                p1[r] = ((unsigned)(iq - j1) <= (unsigned)NB_WIN)
                            ? __expf(s1[r] * 0.125f - 8.f) : 0.f;
                lp += p0[r] + p1[r];
            }
            unsigned P0 = pack_bf16(p0[0], p0[1]), P1 = pack_bf16(p0[2], p0[3]);
            unsigned Q0 = pack_bf16(p1[0], p1[1]), Q1 = pack_bf16(p1[2], p1[3]);

            const int srcA = qi + (g & 1) * 32;
            const int srcB = srcA + 16;
            unsigned tP0a = __shfl((int)P0, srcA, 64), tQ0a = __shfl((int)Q0, srcA, 64);
            unsigned tP1a = __shfl((int)P1, srcA, 64), tQ1a = __shfl((int)Q1, srcA, 64);
            unsigned tP0b = __shfl((int)P0, srcB, 64), tQ0b = __shfl((int)Q0, srcB, 64);
            unsigned tP1b = __shfl((int)P1, srcB, 64), tQ1b = __shfl((int)Q1, srcB, 64);
            union { s16x8 v; unsigned u[4]; } pa;
            pa.u[0] = (g < 2) ? tP0a : tQ0a;
            pa.u[1] = (g < 2) ? tP1a : tQ1a;
            pa.u[2] = (g < 2) ? tP0b : tQ0b;
            pa.u[3] = (g < 2) ? tP1b : tQ1b;

            const int chv = ((g ^ (qi & 3)) << 3);
#pragma unroll
            for (int db = 0; db < 4; ++db) {
                s16x8 bv = *(const s16x8*)&Vs[buf][(db * 16 + qi) * 32 + chv];
                o[db] = __builtin_amdgcn_mfma_f32_16x16x32_bf16(pa.v, bv, o[db], 0, 0, 0);
            }
        }

        SBAR;   // all waves done reading buf before it is restaged next iter
        buf ^= 1;
    }

    float l2 = lp + __shfl_xor(lp, 16, 64);
    float lf = l2 + __shfl_xor(l2, 32, 64);
    float lr[4];
#pragma unroll
    for (int r = 0; r < 4; ++r) lr[r] = __shfl(lf, 4 * g + r, 64);

#pragma unroll
    for (int db = 0; db < 4; ++db)
#pragma unroll
        for (int r = 0; r < 4; ++r) {
            float vlu = o[db][r] / lr[r];
            att[((size_t)(b * 2048 + qw0 + 4 * g + r)) * 1024 + h * 64 + db * 16 + qi] =
                __float2bfloat16(vlu);
        }
}

extern "C" void kernel_launch(void* const* d_in, const int* in_sizes, int n_in,
                              void* d_out, int out_size, void* d_ws, size_t ws_size,
                              hipStream_t stream) {
    const float* x   = (const float*)d_in[0];
    const float* Wq  = (const float*)d_in[1];
    const float* bq  = (const float*)d_in[2];
    const float* Wk  = (const float*)d_in[3];
    const float* bk  = (const float*)d_in[4];
    const float* Wv  = (const float*)d_in[5];
    const float* bv  = (const float*)d_in[6];
    const float* Wo  = (const float*)d_in[7];
    const float* bo  = (const float*)d_in[8];
    const float* lqw = (const float*)d_in[9];
    const float* lqb = (const float*)d_in[10];
    const float* lkw = (const float*)d_in[11];
    const float* lkb = (const float*)d_in[12];

    char* ws = (char*)d_ws;
    bf16* xb    = (bf16*)(ws + 0);               //  8 MB
    bf16* wqkvb = (bf16*)(ws + 8388608);         //  6 MB (Wq|Wk|Wv rows)
    bf16* wob   = (bf16*)(ws + 14680064);        //  2 MB
    bf16* qbuf  = (bf16*)(ws + 16777216);        //  8 MB
    bf16* kbuf  = (bf16*)(ws + 25165824);        //  8 MB
    bf16* vtb   = (bf16*)(ws + 33554432);        //  8 MB
    bf16* attb  = (bf16*)(ws + 41943040);        //  8 MB  (total ~48 MB)

    // all casts in one launch (2M threads)
    k_castall<<<8192, 256, 0, stream>>>(x, Wq, Wk, Wv, Wo, xb, wqkvb, wob);

    // fused QKV projection + bias + QK-LN + V-transpose (counted-vmcnt pipeline)
    k_gemm_qkv<<<dim3(24, 32), 256, 0, stream>>>(xb, wqkvb, bq, bk, bv,
                                                 lqw, lqb, lkw, lkb,
                                                 qbuf, kbuf, vtb);

    // attention: 32 q-tiles x 32 bh = 1024 blocks
    k_attn<<<dim3(32, 32), 256, 0, stream>>>(qbuf, kbuf, vtb, attb);

    // output projection -> f32 d_out (counted-vmcnt pipeline)
    k_gemm_out<<<dim3(8, 32), 256, 0, stream>>>(attb, wob, bo, (float*)d_out);
}